// Round 3
// baseline (53.727 us; speedup 1.0000x reference)
//
#include <hip/hip_runtime.h>
#include <hip/hip_bf16.h>

// B=64, T=2048, D=U=128 (fixed shape)
#define DD 128
#define UU 128
#define SEQ_T 2048
#define ROWS 128
#define PART_STRIDE 132  // per-block partial: [m, l, pad, pad, ctx[128]]

typedef __attribute__((ext_vector_type(8))) short short8;   // 8 bf16 (4 VGPR)
typedef __attribute__((ext_vector_type(4))) float f32x4;    // MFMA C/D

__device__ __forceinline__ unsigned short f2bf(float f) {   // RNE fp32->bf16
  unsigned u = __float_as_uint(f);
  u += 0x7fffu + ((u >> 16) & 1u);
  return (unsigned short)(u >> 16);
}
__device__ __forceinline__ float bf2f(unsigned short s) {
  return __uint_as_float(((unsigned)s) << 16);
}
__device__ __forceinline__ float fast_tanh(float v) {
  float z = __expf(2.0f * v);
  return 1.0f - __fdividef(2.0f, z + 1.0f);
}

// One-shot: Wt[u][d] = bf16(W1[d][u] + W2[d][u]); bias[u] = b1[u]+b2[u]
__global__ void prep_kernel(const float* __restrict__ W1w, const float* __restrict__ W1b,
                            const float* __restrict__ W2w, const float* __restrict__ W2b,
                            unsigned short* __restrict__ wt_g, float* __restrict__ bias_g)
{
  int i = blockIdx.x * 256 + threadIdx.x;   // 16384 = 128*128
  int u = i >> 7, d = i & 127;
  float s = W1w[(size_t)d * UU + u] + W2w[(size_t)d * UU + u];
  wt_g[(size_t)u * DD + d] = f2bf(s);
  if (i < UU) bias_g[i] = W1b[i] + W2b[i];
}

// Fused: h = tanh(x@Wsum + bias); s = h@V; block softmax partial + context.
// 128 rows/block, 4 waves. x staged bf16 in swizzled LDS (read HBM once);
// B-fragments straight from global (L2-resident 32KB) -> only ~36KB LDS
// -> 4 blocks/CU for memory-latency hiding.
__global__ __launch_bounds__(256, 4)
void fused_score_ctx(const float* __restrict__ x,
                     const unsigned short* __restrict__ wt_g,
                     const float* __restrict__ bias_g,
                     const float* __restrict__ Vw,
                     float* __restrict__ part)
{
  __shared__ __align__(16) unsigned short xs[ROWS * DD];  // 32 KB, swizzled bf16
  __shared__ float bsum[UU];
  __shared__ float vv[UU];
  __shared__ float slds[ROWS];
  __shared__ float pctx_red[4][DD];  // per-wave context partials
  __shared__ float red[8];

  const int tid = threadIdx.x;
  const int blk = blockIdx.x;
  const int rowbase = blk * ROWS;

  if (tid < UU) { bsum[tid] = bias_g[tid]; vv[tid] = Vw[tid]; }

  // ---- stage x (fp32 -> bf16, XOR-swizzled granules of 8 elems) ----
  #pragma unroll
  for (int it = 0; it < 8; ++it) {
    int F = tid + 256 * it;            // 2048 granules
    int row = F >> 4, g = F & 15;
    const float* src = x + (size_t)(rowbase + row) * DD + g * 8;
    const float4 v0 = *reinterpret_cast<const float4*>(src);
    const float4 v1 = *reinterpret_cast<const float4*>(src + 4);
    short8 pk;
    pk[0] = (short)f2bf(v0.x); pk[1] = (short)f2bf(v0.y);
    pk[2] = (short)f2bf(v0.z); pk[3] = (short)f2bf(v0.w);
    pk[4] = (short)f2bf(v1.x); pk[5] = (short)f2bf(v1.y);
    pk[6] = (short)f2bf(v1.z); pk[7] = (short)f2bf(v1.w);
    *reinterpret_cast<short8*>(xs + row * DD + ((g ^ (row & 15)) << 3)) = pk;
  }
  __syncthreads();

  // ---- MFMA GEMM: per wave 32 rows x 128 u; B direct from global (L2) ----
  const int w = tid >> 6, l = tid & 63, lx = l & 15, lq = l >> 4;
  f32x4 acc[2][8];
  #pragma unroll
  for (int mf = 0; mf < 2; ++mf)
    #pragma unroll
    for (int nf = 0; nf < 8; ++nf) acc[mf][nf] = (f32x4){0.f, 0.f, 0.f, 0.f};

  const int arow0 = w * 32 + lx;
  #pragma unroll
  for (int kf = 0; kf < 4; ++kf) {
    const int gs8 = ((kf * 4 + lq) ^ lx) << 3;   // swizzled granule offset (elems)
    short8 a0 = *reinterpret_cast<const short8*>(xs + arow0 * DD + gs8);
    short8 a1 = *reinterpret_cast<const short8*>(xs + (arow0 + 16) * DD + gs8);
    short8 b[8];
    #pragma unroll
    for (int nf = 0; nf < 8; ++nf)
      b[nf] = *reinterpret_cast<const short8*>(
          wt_g + (size_t)(nf * 16 + lx) * DD + (kf * 4 + lq) * 8);
    #pragma unroll
    for (int nf = 0; nf < 8; ++nf) {
      acc[0][nf] = __builtin_amdgcn_mfma_f32_16x16x32_bf16(a0, b[nf], acc[0][nf], 0, 0, 0);
      acc[1][nf] = __builtin_amdgcn_mfma_f32_16x16x32_bf16(a1, b[nf], acc[1][nf], 0, 0, 0);
    }
  }

  // ---- scores: s[row] = sum_u V[u] * tanh(h[row][u] + bias[u]) ----
  float vs[8], bs[8];
  #pragma unroll
  for (int nf = 0; nf < 8; ++nf) { vs[nf] = vv[nf * 16 + lx]; bs[nf] = bsum[nf * 16 + lx]; }
  #pragma unroll
  for (int mf = 0; mf < 2; ++mf) {
    #pragma unroll
    for (int r = 0; r < 4; ++r) {
      float p = 0.0f;
      #pragma unroll
      for (int nf = 0; nf < 8; ++nf)
        p += vs[nf] * fast_tanh(acc[mf][nf][r] + bs[nf]);
      p += __shfl_xor(p, 1);
      p += __shfl_xor(p, 2);
      p += __shfl_xor(p, 4);
      p += __shfl_xor(p, 8);
      if (lx == 0) slds[w * 32 + mf * 16 + lq * 4 + r] = p;  // C/D row=(lq*4+r)
    }
  }
  __syncthreads();

  // ---- block-local softmax stats (m, l) ----
  float sv = slds[tid & 127];
  float m = sv;
  #pragma unroll
  for (int off = 1; off < 64; off <<= 1) m = fmaxf(m, __shfl_xor(m, off));
  if ((tid & 63) == 0) red[tid >> 6] = m;
  __syncthreads();
  m = fmaxf(fmaxf(red[0], red[1]), fmaxf(red[2], red[3]));

  float e = (tid < 128) ? __expf(sv - m) : 0.0f;  // each row counted once
  float lsum = e;
  #pragma unroll
  for (int off = 1; off < 64; off <<= 1) lsum += __shfl_xor(lsum, off);
  if ((tid & 63) == 0) red[4 + (tid >> 6)] = lsum;
  __syncthreads();
  lsum = (red[4] + red[5]) + (red[6] + red[7]);

  if (tid < 128) slds[tid] = e;
  __syncthreads();

  // ---- partial context: vectorized. thread = (t-group tg, d-granule gd) ----
  {
    const int gd = tid & 15;          // logical d-granule (8 d's)
    const int tg = tid >> 4;          // 16 t-groups of 8 t; wave w owns tg 4w..4w+3
    float ca[8];
    #pragma unroll
    for (int e2 = 0; e2 < 8; ++e2) ca[e2] = 0.0f;
    #pragma unroll
    for (int k = 0; k < 8; ++k) {
      int t = tg * 8 + k;
      float wgt = slds[t];
      short8 xv = *reinterpret_cast<const short8*>(xs + t * DD + ((gd ^ (t & 15)) << 3));
      #pragma unroll
      for (int e2 = 0; e2 < 8; ++e2)
        ca[e2] = fmaf(wgt, bf2f((unsigned short)xv[e2]), ca[e2]);
    }
    // reduce the 4 in-wave t-groups (lane = (tg&3)*16 + gd)
    #pragma unroll
    for (int e2 = 0; e2 < 8; ++e2) {
      ca[e2] += __shfl_xor(ca[e2], 16);
      ca[e2] += __shfl_xor(ca[e2], 32);
    }
    if ((l >> 4) == 0) {   // one lane-group per wave writes its partial
      #pragma unroll
      for (int e2 = 0; e2 < 8; ++e2) pctx_red[w][gd * 8 + e2] = ca[e2];
    }
  }
  __syncthreads();

  float* prec = part + (size_t)blk * PART_STRIDE;
  if (tid < 128) {
    float c0 = (pctx_red[0][tid] + pctx_red[1][tid]) +
               (pctx_red[2][tid] + pctx_red[3][tid]);
    prec[4 + tid] = c0;
  }
  if (tid == 0) { prec[0] = m; prec[1] = lsum; }
}

// Flash-style combine of 16 per-block partials per batch row.
__global__ void combine_kernel(const float* __restrict__ part,
                               float* __restrict__ out, int chunks)
{
  int b = blockIdx.x;
  int d = threadIdx.x;  // 128
  float mg = -3.0e38f;
  for (int i = 0; i < chunks; ++i)
    mg = fmaxf(mg, part[(size_t)(b * chunks + i) * PART_STRIDE]);
  float den = 0.0f, num = 0.0f;
  for (int i = 0; i < chunks; ++i) {
    const float* p = part + (size_t)(b * chunks + i) * PART_STRIDE;
    float sc = __expf(p[0] - mg);
    den = fmaf(sc, p[1], den);
    num = fmaf(sc, p[4 + d], num);
  }
  out[(size_t)b * DD + d] = __fdividef(num, den);
}

extern "C" void kernel_launch(void* const* d_in, const int* in_sizes, int n_in,
                              void* d_out, int out_size, void* d_ws, size_t ws_size,
                              hipStream_t stream)
{
  const float* x   = (const float*)d_in[0];
  const float* W1w = (const float*)d_in[1];
  const float* W1b = (const float*)d_in[2];
  const float* W2w = (const float*)d_in[3];
  const float* W2b = (const float*)d_in[4];
  const float* Vw  = (const float*)d_in[5];
  // d_in[6] = V_b: constant on scores, cancels in softmax.

  const int bt = in_sizes[0] / DD;   // 131072
  const int nblk = bt / ROWS;        // 1024
  const int B = bt / SEQ_T;          // 64
  const int chunks = SEQ_T / ROWS;   // 16

  float* part = (float*)d_ws;                                        // 540672 B
  unsigned short* wt_g = (unsigned short*)((char*)d_ws + 540672);    // 32768 B
  float* bias_g = (float*)((char*)d_ws + 540672 + 32768);            // 512 B

  prep_kernel<<<64, 256, 0, stream>>>(W1w, W1b, W2w, W2b, wt_g, bias_g);
  fused_score_ctx<<<nblk, 256, 0, stream>>>(x, wt_g, bias_g, Vw, part);
  combine_kernel<<<B, 128, 0, stream>>>(part, (float*)d_out, chunks);
}

// Round 4
// 45.084 us; speedup vs baseline: 1.1917x; 1.1917x over previous
//
#include <hip/hip_runtime.h>
#include <hip/hip_bf16.h>

// B=64, T=2048, D=U=128 (fixed shape)
#define DD 128
#define UU 128
#define SEQ_T 2048
#define ROWS 128          // rows per tile
#define NTILE 4           // tiles per persistent block
#define GRID 256          // 256 blocks * 4 tiles * 128 rows = 131072 rows
#define PART_STRIDE 132   // per-tile partial: [m, l, pad, pad, ctx[128]]

typedef __attribute__((ext_vector_type(8))) short short8;   // 8 bf16
typedef __attribute__((ext_vector_type(4))) float f32x4;    // MFMA C/D

__device__ __forceinline__ unsigned short f2bf(float f) {   // RNE fp32->bf16
  unsigned u = __float_as_uint(f);
  u += 0x7fffu + ((u >> 16) & 1u);
  return (unsigned short)(u >> 16);
}
__device__ __forceinline__ float bf2f(unsigned short s) {
  return __uint_as_float(((unsigned)s) << 16);
}
__device__ __forceinline__ float fast_tanh(float v) {
  float z = __expf(2.0f * v);
  return 1.0f - __fdividef(2.0f, z + 1.0f);
}

// One-shot: Wt[u][d] = bf16(W1[d][u] + W2[d][u]); bias[u] = b1[u]+b2[u]
__global__ void prep_kernel(const float* __restrict__ W1w, const float* __restrict__ W1b,
                            const float* __restrict__ W2w, const float* __restrict__ W2b,
                            unsigned short* __restrict__ wt_g, float* __restrict__ bias_g)
{
  int i = blockIdx.x * 256 + threadIdx.x;   // 16384 = 128*128
  int u = i >> 7, d = i & 127;
  float s = W1w[(size_t)d * UU + u] + W2w[(size_t)d * UU + u];
  wt_g[(size_t)u * DD + d] = f2bf(s);
  if (i < UU) bias_g[i] = W1b[i] + W2b[i];
}

// Persistent fused kernel: 8 waves, 4 tiles of 128 rows, double-buffered x
// staging (issue-early loads hide HBM latency under GEMM+epilogue).
__global__ __launch_bounds__(512, 2)
void fused_score_ctx(const float* __restrict__ x,
                     const unsigned short* __restrict__ wt_g,
                     const float* __restrict__ bias_g,
                     const float* __restrict__ Vw,
                     float* __restrict__ part)
{
  __shared__ __align__(16) unsigned short wt[UU * DD];        // 32 KB swizzled
  __shared__ __align__(16) unsigned short xs[2][ROWS * DD];   // 2x32 KB swizzled
  __shared__ float bsum[UU];
  __shared__ float vv[UU];
  __shared__ float slds[ROWS];
  __shared__ float pctx_red[8][DD];
  __shared__ float red[16];

  const int tid = threadIdx.x;
  const int blk = blockIdx.x;
  const int w = tid >> 6, l = tid & 63, lx = l & 15, lq = l >> 4;

  if (tid < UU) { bsum[tid] = bias_g[tid]; vv[tid] = Vw[tid]; }

  const float* xbase = x + (size_t)(blk * NTILE * ROWS) * DD;

  // ---- prologue: issue tile-0 loads (8 float4/thread), then stage wt ----
  float4 xr[8];
  #pragma unroll
  for (int gi = 0; gi < 4; ++gi) {
    int F = tid + 512 * gi;            // 2048 granules of 8 elems
    int row = F >> 4, g = F & 15;
    const float* src = xbase + (size_t)row * DD + g * 8;
    xr[2 * gi]     = *reinterpret_cast<const float4*>(src);
    xr[2 * gi + 1] = *reinterpret_cast<const float4*>(src + 4);
  }
  #pragma unroll
  for (int gi = 0; gi < 4; ++gi) {
    int F = tid + 512 * gi;
    int u = F >> 4, g = F & 15;
    short8 wv = *reinterpret_cast<const short8*>(wt_g + (size_t)F * 8);
    *reinterpret_cast<short8*>(wt + u * DD + ((g ^ (u & 15)) << 3)) = wv;
  }

  for (int t = 0; t < NTILE; ++t) {
    unsigned short* xb = xs[t & 1];

    // ---- write phase: cvt staged regs -> swizzled LDS ----
    #pragma unroll
    for (int gi = 0; gi < 4; ++gi) {
      int F = tid + 512 * gi;
      int row = F >> 4, g = F & 15;
      float4 v0 = xr[2 * gi], v1 = xr[2 * gi + 1];
      short8 pk;
      pk[0] = (short)f2bf(v0.x); pk[1] = (short)f2bf(v0.y);
      pk[2] = (short)f2bf(v0.z); pk[3] = (short)f2bf(v0.w);
      pk[4] = (short)f2bf(v1.x); pk[5] = (short)f2bf(v1.y);
      pk[6] = (short)f2bf(v1.z); pk[7] = (short)f2bf(v1.w);
      *reinterpret_cast<short8*>(xb + row * DD + ((g ^ (row & 15)) << 3)) = pk;
    }
    __syncthreads();   // xs[t&1] + (t==0: wt, bsum, vv) visible

    // ---- issue next-tile loads; in flight across GEMM+epilogue ----
    if (t + 1 < NTILE) {
      const float* nb = xbase + (size_t)((t + 1) * ROWS) * DD;
      #pragma unroll
      for (int gi = 0; gi < 4; ++gi) {
        int F = tid + 512 * gi;
        int row = F >> 4, g = F & 15;
        const float* src = nb + (size_t)row * DD + g * 8;
        xr[2 * gi]     = *reinterpret_cast<const float4*>(src);
        xr[2 * gi + 1] = *reinterpret_cast<const float4*>(src + 4);
      }
    }

    // ---- GEMM: wave w -> rows 16w..16w+15, all 128 u ----
    f32x4 acc[8];
    #pragma unroll
    for (int nf = 0; nf < 8; ++nf) acc[nf] = (f32x4){0.f, 0.f, 0.f, 0.f};
    const int arow = w * 16 + lx;
    #pragma unroll
    for (int kf = 0; kf < 4; ++kf) {
      const int gs8 = ((kf * 4 + lq) ^ lx) << 3;
      short8 a = *reinterpret_cast<const short8*>(xb + arow * DD + gs8);
      #pragma unroll
      for (int nf = 0; nf < 8; ++nf) {
        short8 b = *reinterpret_cast<const short8*>(wt + (nf * 16 + lx) * DD + gs8);
        acc[nf] = __builtin_amdgcn_mfma_f32_16x16x32_bf16(a, b, acc[nf], 0, 0, 0);
      }
    }

    // ---- scores: s[row] = sum_u V[u]*tanh(h+bias) ----
    float vs[8], bs[8];
    #pragma unroll
    for (int nf = 0; nf < 8; ++nf) { vs[nf] = vv[nf * 16 + lx]; bs[nf] = bsum[nf * 16 + lx]; }
    #pragma unroll
    for (int r = 0; r < 4; ++r) {
      float pp = 0.0f;
      #pragma unroll
      for (int nf = 0; nf < 8; ++nf)
        pp += vs[nf] * fast_tanh(acc[nf][r] + bs[nf]);
      pp += __shfl_xor(pp, 1);
      pp += __shfl_xor(pp, 2);
      pp += __shfl_xor(pp, 4);
      pp += __shfl_xor(pp, 8);
      if (lx == 0) slds[w * 16 + lq * 4 + r] = pp;   // C/D row = lq*4+r
    }
    __syncthreads();

    // ---- block softmax stats over 128 rows ----
    float sv = slds[tid & 127];
    float m = sv;
    #pragma unroll
    for (int off = 1; off < 64; off <<= 1) m = fmaxf(m, __shfl_xor(m, off));
    if (l == 0) red[w] = m;
    __syncthreads();
    m = red[0];
    #pragma unroll
    for (int i = 1; i < 8; ++i) m = fmaxf(m, red[i]);

    float e = (tid < 128) ? __expf(sv - m) : 0.0f;   // each row counted once
    float lsum = e;
    #pragma unroll
    for (int off = 1; off < 64; off <<= 1) lsum += __shfl_xor(lsum, off);
    if (l == 0) red[8 + w] = lsum;
    __syncthreads();
    lsum = 0.0f;
    #pragma unroll
    for (int i = 0; i < 8; ++i) lsum += red[8 + i];

    if (tid < 128) slds[tid] = e;
    __syncthreads();

    // ---- partial context: thread = (t-group of 4 rows, d-granule) ----
    {
      const int gd = tid & 15;         // d-granule (8 d's)
      const int tg = tid >> 4;         // 32 groups of 4 rows
      float ca[8];
      #pragma unroll
      for (int e2 = 0; e2 < 8; ++e2) ca[e2] = 0.0f;
      #pragma unroll
      for (int k = 0; k < 4; ++k) {
        int tt = tg * 4 + k;
        float wgt = slds[tt];
        short8 xv = *reinterpret_cast<const short8*>(
            xb + tt * DD + ((gd ^ (tt & 15)) << 3));
        #pragma unroll
        for (int e2 = 0; e2 < 8; ++e2)
          ca[e2] = fmaf(wgt, bf2f((unsigned short)xv[e2]), ca[e2]);
      }
      #pragma unroll
      for (int e2 = 0; e2 < 8; ++e2) {
        ca[e2] += __shfl_xor(ca[e2], 16);
        ca[e2] += __shfl_xor(ca[e2], 32);
      }
      if (l < 16) {
        #pragma unroll
        for (int e2 = 0; e2 < 8; ++e2) pctx_red[w][l * 8 + e2] = ca[e2];
      }
    }
    __syncthreads();

    float* prec = part + (size_t)(blk * NTILE + t) * PART_STRIDE;
    if (tid < 128) {
      float c0 = 0.0f;
      #pragma unroll
      for (int i = 0; i < 8; ++i) c0 += pctx_red[i][tid];
      prec[4 + tid] = c0;
    }
    if (tid == 0) { prec[0] = m; prec[1] = lsum; }
    // next iter writes xs[(t+1)&1] (other buffer); reuse of this buffer is
    // two barriers away -> safe.
  }
}

// Flash-style combine of 16 per-tile partials per batch row.
__global__ void combine_kernel(const float* __restrict__ part,
                               float* __restrict__ out, int chunks)
{
  int b = blockIdx.x;
  int d = threadIdx.x;  // 128
  float mg = -3.0e38f;
  for (int i = 0; i < chunks; ++i)
    mg = fmaxf(mg, part[(size_t)(b * chunks + i) * PART_STRIDE]);
  float den = 0.0f, num = 0.0f;
  for (int i = 0; i < chunks; ++i) {
    const float* p = part + (size_t)(b * chunks + i) * PART_STRIDE;
    float sc = __expf(p[0] - mg);
    den = fmaf(sc, p[1], den);
    num = fmaf(sc, p[4 + d], num);
  }
  out[(size_t)b * DD + d] = __fdividef(num, den);
}

extern "C" void kernel_launch(void* const* d_in, const int* in_sizes, int n_in,
                              void* d_out, int out_size, void* d_ws, size_t ws_size,
                              hipStream_t stream)
{
  const float* x   = (const float*)d_in[0];
  const float* W1w = (const float*)d_in[1];
  const float* W1b = (const float*)d_in[2];
  const float* W2w = (const float*)d_in[3];
  const float* W2b = (const float*)d_in[4];
  const float* Vw  = (const float*)d_in[5];
  // d_in[6] = V_b: constant on scores, cancels in softmax.

  const int bt = in_sizes[0] / DD;   // 131072
  const int B = bt / SEQ_T;          // 64
  const int chunks = SEQ_T / ROWS;   // 16

  float* part = (float*)d_ws;                                        // 540672 B
  unsigned short* wt_g = (unsigned short*)((char*)d_ws + 540672);    // 32768 B
  float* bias_g = (float*)((char*)d_ws + 540672 + 32768);            // 512 B

  prep_kernel<<<64, 256, 0, stream>>>(W1w, W1b, W2w, W2b, wt_g, bias_g);
  fused_score_ctx<<<GRID, 512, 0, stream>>>(x, wt_g, bias_g, Vw, part);
  combine_kernel<<<B, 128, 0, stream>>>(part, (float*)d_out, chunks);
}

// Round 6
// 40.603 us; speedup vs baseline: 1.3232x; 1.1104x over previous
//
#include <hip/hip_runtime.h>
#include <hip/hip_bf16.h>

// B=64, T=2048, D=U=128 (fixed shape)
#define DD 128
#define UU 128
#define SEQ_T 2048
#define ROWS 128
#define PART_STRIDE 132   // per-block partial: [m, l, pad, pad, ctx[128]]

typedef __attribute__((ext_vector_type(8))) short short8;   // 8 bf16
typedef __attribute__((ext_vector_type(4))) float f32x4;    // MFMA C/D

__device__ __forceinline__ unsigned short f2bf(float f) {   // RNE fp32->bf16
  unsigned u = __float_as_uint(f);
  u += 0x7fffu + ((u >> 16) & 1u);
  return (unsigned short)(u >> 16);
}
__device__ __forceinline__ float bf2f(unsigned short s) {
  return __uint_as_float(((unsigned)s) << 16);
}
__device__ __forceinline__ float fast_tanh(float v) {
  float z = __expf(2.0f * v);
  return 1.0f - __fdividef(2.0f, z + 1.0f);
}

// One-shot: Wt[u][d] = bf16(W1[d][u] + W2[d][u]); bias[u] = b1[u]+b2[u]
__global__ void prep_kernel(const float* __restrict__ W1w, const float* __restrict__ W1b,
                            const float* __restrict__ W2w, const float* __restrict__ W2b,
                            unsigned short* __restrict__ wt_g, float* __restrict__ bias_g)
{
  int i = blockIdx.x * 256 + threadIdx.x;   // 16384 = 128*128
  int u = i >> 7, d = i & 127;
  float s = W1w[(size_t)d * UU + u] + W2w[(size_t)d * UU + u];
  wt_g[(size_t)u * DD + d] = f2bf(s);
  if (i < UU) bias_g[i] = W1b[i] + W2b[i];
}

// Fused: 128 rows/block, 4 waves (1m x 4n: wave w owns u in [32w,32w+32)).
// B-fragments live in 32 VGPRs (loaded once, L2-hit); only the x tile is in
// LDS (~38 KB) -> 3 blocks/CU; cross-block TLP overlaps HBM/VALU/trans/LDS.
__global__ __launch_bounds__(256, 3)
void fused_score_ctx(const float* __restrict__ x,
                     const unsigned short* __restrict__ wt_g,
                     const float* __restrict__ bias_g,
                     const float* __restrict__ Vw,
                     float* __restrict__ part)
{
  __shared__ __align__(16) unsigned short xs[ROWS * DD];  // 32 KB swizzled bf16
  __shared__ __align__(16) float spart[4][ROWS];          // per-wave score partials
  __shared__ float slds[ROWS];
  __shared__ float pctx_red[4][DD];
  __shared__ float red[8];

  const int tid = threadIdx.x;
  const int blk = blockIdx.x;
  const int rowbase = blk * ROWS;
  const int w = tid >> 6, l = tid & 63, lx = l & 15, lq = l >> 4;

  // ---- B fragments + V/bias scalars for this wave's 32 u-columns ----
  short8 Bf[2][4];
  float vs[2], bs[2];
  #pragma unroll
  for (int nf = 0; nf < 2; ++nf) {
    const int u = 32 * w + 16 * nf + lx;
    vs[nf] = Vw[u];
    bs[nf] = bias_g[u];
    #pragma unroll
    for (int kf = 0; kf < 4; ++kf)
      Bf[nf][kf] = *reinterpret_cast<const short8*>(
          wt_g + (size_t)u * DD + 32 * kf + 8 * lq);
  }

  // ---- stage x (fp32 -> bf16, XOR-swizzled 8-elem granules) ----
  #pragma unroll
  for (int it = 0; it < 8; ++it) {
    int F = tid + 256 * it;            // 2048 granules
    int row = F >> 4, g = F & 15;
    const float* src = x + (size_t)(rowbase + row) * DD + g * 8;
    const float4 v0 = *reinterpret_cast<const float4*>(src);
    const float4 v1 = *reinterpret_cast<const float4*>(src + 4);
    short8 pk;
    pk[0] = (short)f2bf(v0.x); pk[1] = (short)f2bf(v0.y);
    pk[2] = (short)f2bf(v0.z); pk[3] = (short)f2bf(v0.w);
    pk[4] = (short)f2bf(v1.x); pk[5] = (short)f2bf(v1.y);
    pk[6] = (short)f2bf(v1.z); pk[7] = (short)f2bf(v1.w);
    *reinterpret_cast<short8*>(xs + row * DD + ((g ^ (row & 15)) << 3)) = pk;
  }
  __syncthreads();

  // ---- GEMM: all 128 rows x this wave's 32 u; zero VMEM in loop ----
  f32x4 acc[8][2];
  #pragma unroll
  for (int mf = 0; mf < 8; ++mf) {
    acc[mf][0] = (f32x4){0.f, 0.f, 0.f, 0.f};
    acc[mf][1] = (f32x4){0.f, 0.f, 0.f, 0.f};
  }
  #pragma unroll
  for (int kf = 0; kf < 4; ++kf) {
    const int gs8 = ((4 * kf + lq) ^ lx) << 3;   // row&15 == lx
    #pragma unroll
    for (int mf = 0; mf < 8; ++mf) {
      short8 a = *reinterpret_cast<const short8*>(xs + (16 * mf + lx) * DD + gs8);
      acc[mf][0] = __builtin_amdgcn_mfma_f32_16x16x32_bf16(a, Bf[0][kf], acc[mf][0], 0, 0, 0);
      acc[mf][1] = __builtin_amdgcn_mfma_f32_16x16x32_bf16(a, Bf[1][kf], acc[mf][1], 0, 0, 0);
    }
  }

  // ---- per-wave score partials: p[row] = sum_{u in wave} V*tanh(h+bias) ----
  #pragma unroll
  for (int mf = 0; mf < 8; ++mf) {
    f32x4 pv;
    #pragma unroll
    for (int r = 0; r < 4; ++r) {
      float p = vs[0] * fast_tanh(acc[mf][0][r] + bs[0])
              + vs[1] * fast_tanh(acc[mf][1][r] + bs[1]);
      p += __shfl_xor(p, 1);
      p += __shfl_xor(p, 2);
      p += __shfl_xor(p, 4);
      p += __shfl_xor(p, 8);
      pv[r] = p;
    }
    if (lx == 0)   // rows 16mf + 4lq .. +3
      *reinterpret_cast<f32x4*>(&spart[w][16 * mf + 4 * lq]) = pv;
  }
  __syncthreads();

  // ---- total scores + block softmax stats ----
  const int rr = tid & 127;
  float sv = (spart[0][rr] + spart[1][rr]) + (spart[2][rr] + spart[3][rr]);
  float m = sv;
  #pragma unroll
  for (int off = 1; off < 64; off <<= 1) m = fmaxf(m, __shfl_xor(m, off));
  if (l == 0) red[w] = m;
  __syncthreads();
  m = fmaxf(fmaxf(red[0], red[1]), fmaxf(red[2], red[3]));

  float e = (tid < 128) ? __expf(sv - m) : 0.0f;   // each row counted once
  float lsum = e;
  #pragma unroll
  for (int off = 1; off < 64; off <<= 1) lsum += __shfl_xor(lsum, off);
  if (l == 0) red[4 + w] = lsum;
  __syncthreads();
  lsum = (red[4] + red[5]) + (red[6] + red[7]);

  if (tid < 128) slds[tid] = e;
  __syncthreads();

  // ---- partial context: thread = (t-group of 8 rows, d-granule) ----
  {
    const int gd = tid & 15;          // d-granule (8 d's)
    const int tg = tid >> 4;          // 16 groups of 8 rows
    float ca[8];
    #pragma unroll
    for (int e2 = 0; e2 < 8; ++e2) ca[e2] = 0.0f;
    #pragma unroll
    for (int k = 0; k < 8; ++k) {
      int t = tg * 8 + k;
      float wgt = slds[t];
      short8 xv = *reinterpret_cast<const short8*>(xs + t * DD + ((gd ^ (t & 15)) << 3));
      #pragma unroll
      for (int e2 = 0; e2 < 8; ++e2)
        ca[e2] = fmaf(wgt, bf2f((unsigned short)xv[e2]), ca[e2]);
    }
    #pragma unroll
    for (int e2 = 0; e2 < 8; ++e2) {
      ca[e2] += __shfl_xor(ca[e2], 16);
      ca[e2] += __shfl_xor(ca[e2], 32);
    }
    if ((l >> 4) == 0) {
      #pragma unroll
      for (int e2 = 0; e2 < 8; ++e2) pctx_red[w][gd * 8 + e2] = ca[e2];
    }
  }
  __syncthreads();

  float* prec = part + (size_t)blk * PART_STRIDE;
  if (tid < 128) {
    float c0 = (pctx_red[0][tid] + pctx_red[1][tid]) +
               (pctx_red[2][tid] + pctx_red[3][tid]);
    prec[4 + tid] = c0;
  }
  if (tid == 0) { prec[0] = m; prec[1] = lsum; }
}

// Flash-style combine of 16 per-block partials per batch row.
__global__ void combine_kernel(const float* __restrict__ part,
                               float* __restrict__ out, int chunks)
{
  int b = blockIdx.x;
  int d = threadIdx.x;  // 128
  float mg = -3.0e38f;
  for (int i = 0; i < chunks; ++i)
    mg = fmaxf(mg, part[(size_t)(b * chunks + i) * PART_STRIDE]);
  float den = 0.0f, num = 0.0f;
  for (int i = 0; i < chunks; ++i) {
    const float* p = part + (size_t)(b * chunks + i) * PART_STRIDE;
    float sc = __expf(p[0] - mg);
    den = fmaf(sc, p[1], den);
    num = fmaf(sc, p[4 + d], num);
  }
  out[(size_t)b * DD + d] = __fdividef(num, den);
}

extern "C" void kernel_launch(void* const* d_in, const int* in_sizes, int n_in,
                              void* d_out, int out_size, void* d_ws, size_t ws_size,
                              hipStream_t stream)
{
  const float* x   = (const float*)d_in[0];
  const float* W1w = (const float*)d_in[1];
  const float* W1b = (const float*)d_in[2];
  const float* W2w = (const float*)d_in[3];
  const float* W2b = (const float*)d_in[4];
  const float* Vw  = (const float*)d_in[5];
  // d_in[6] = V_b: constant on scores, cancels in softmax.

  const int bt = in_sizes[0] / DD;   // 131072
  const int nblk = bt / ROWS;        // 1024
  const int B = bt / SEQ_T;          // 64
  const int chunks = SEQ_T / ROWS;   // 16

  float* part = (float*)d_ws;                                        // 540672 B
  unsigned short* wt_g = (unsigned short*)((char*)d_ws + 540672);    // 32768 B
  float* bias_g = (float*)((char*)d_ws + 540672 + 32768);            // 512 B

  prep_kernel<<<64, 256, 0, stream>>>(W1w, W1b, W2w, W2b, wt_g, bias_g);
  fused_score_ctx<<<nblk, 256, 0, stream>>>(x, wt_g, bias_g, Vw, part);
  combine_kernel<<<B, 128, 0, stream>>>(part, (float*)d_out, chunks);
}